// Round 21
// baseline (384.440 us; speedup 1.0000x reference)
//
#include <hip/hip_runtime.h>
#include <math.h>

typedef unsigned short u16;
typedef unsigned int   u32;
typedef __attribute__((ext_vector_type(8))) short bf16x8;  // 8 bf16 (4 VGPRs)
typedef __attribute__((ext_vector_type(4))) float f32x4;

__device__ __forceinline__ u16 f2bf(float f) {
  u32 u = __builtin_bit_cast(u32, f);
  u += 0x7fffu + ((u >> 16) & 1u);   // RNE
  return (u16)(u >> 16);
}
__device__ __forceinline__ u32 cvtpk(float lo, float hi_) {
  u32 r;
  asm("v_cvt_pk_bf16_f32 %0, %1, %2" : "=v"(r) : "v"(lo), "v"(hi_));
  return r;
}
// Abramowitz-Stegun 7.1.26, |err| < 1.5e-7 (negligible vs bf16 rounding)
__device__ __forceinline__ float erf_fast(float x) {
  const float ax = fabsf(x);
  const float tt = 1.0f / fmaf(0.3275911f, ax, 1.0f);
  float p = fmaf(1.061405429f, tt, -1.453152027f);
  p = fmaf(p, tt, 1.421413741f);
  p = fmaf(p, tt, -0.284496736f);
  p = fmaf(p, tt, 0.254829592f);
  const float r = 1.0f - p * tt * __expf(-ax * ax);
  return copysignf(r, x);
}

// async global->LDS, 16B per lane. LDS dest must be wave-uniform; HW writes
// lane l's 16B at dest + l*16 (linear). Global src is per-lane.
__device__ __forceinline__ void g2l16(const u16* g, u16* l) {
  __builtin_amdgcn_global_load_lds(
      (const __attribute__((address_space(1))) unsigned int*)g,
      (__attribute__((address_space(3))) unsigned int*)l, 16, 0, 0);
}

// ---------------- batched transpose+convert for 8x [1024][1024] weights ------
struct TC8 { const float* s[8]; u16* d[8]; };
__global__ __launch_bounds__(256)
void transcvt8_kernel(TC8 p) {
  const float* __restrict__ W = p.s[blockIdx.z];
  u16* __restrict__ Wt = p.d[blockIdx.z];
  __shared__ float tile[32][33];
  const int n0 = blockIdx.x * 32, k0 = blockIdx.y * 32;
  const int tx = threadIdx.x & 31, ty = threadIdx.x >> 5;  // 32 x 8
  for (int i = 0; i < 4; ++i)
    tile[ty + 8 * i][tx] = W[(size_t)(k0 + ty + 8 * i) * 1024 + n0 + tx];
  __syncthreads();
  for (int i = 0; i < 4; ++i)
    Wt[(size_t)(n0 + ty + 8 * i) * 1024 + k0 + tx] = f2bf(tile[tx][ty + 8 * i]);
}

// ---------------- transpose + convert: W[K][N] f32 -> Wt[N][K] bf16 ----------
__global__ __launch_bounds__(256)
void transcvt_kernel(const float* __restrict__ W, u16* __restrict__ Wt, int K, int N) {
  __shared__ float tile[32][33];
  const int n0 = blockIdx.x * 32, k0 = blockIdx.y * 32;
  const int tx = threadIdx.x & 31, ty = threadIdx.x >> 5;
  for (int i = 0; i < 4; ++i)
    tile[ty + 8 * i][tx] = W[(size_t)(k0 + ty + 8 * i) * N + n0 + tx];
  __syncthreads();
  for (int i = 0; i < 4; ++i)
    Wt[(size_t)(n0 + ty + 8 * i) * K + k0 + tx] = f2bf(tile[tx][ty + 8 * i]);
}

// ---------------- elementwise convert f32 -> bf16 ----------------------------
__global__ __launch_bounds__(256)
void cvt_kernel(const float* __restrict__ in, u16* __restrict__ out) {
  const int i = blockIdx.x * 256 + threadIdx.x;
  const float4 v = ((const float4*)in)[i];
  u16 o[4] = {f2bf(v.x), f2bf(v.y), f2bf(v.z), f2bf(v.w)};
  ((ushort4*)out)[i] = *(ushort4*)o;
}

// ---------------- bias packing (B3: [bq|0|bv], B2: [0|bv]) ------------------
__global__ __launch_bounds__(256)
void pack_bias_kernel(const float* __restrict__ bq, const float* __restrict__ bv,
                      const float* __restrict__ cbv,
                      float* __restrict__ B3, float* __restrict__ B2) {
  const int i = blockIdx.x * 256 + threadIdx.x;   // 5120 total
  if (i < 3072) {
    float v = 0.0f;
    if (i < 1024) v = bq[i];
    else if (i >= 2048) v = bv[i - 2048];
    B3[i] = v;
  } else {
    const int j = i - 3072;
    B2[j] = (j >= 1024) ? cbv[j - 1024] : 0.0f;
  }
}

// ---------------- LayerNorm: rows of 1024, f32 in -> bf16 out ---------------
__global__ __launch_bounds__(256)
void ln_kernel(const float* __restrict__ x, const float* __restrict__ g,
               const float* __restrict__ b, u16* __restrict__ out) {
  const int row = blockIdx.x;
  const float4 v4 = ((const float4*)(x + (size_t)row * 1024))[threadIdx.x];
  float vv[4] = {v4.x, v4.y, v4.z, v4.w};
  float s = vv[0] + vv[1] + vv[2] + vv[3];
  float s2 = vv[0] * vv[0] + vv[1] * vv[1] + vv[2] * vv[2] + vv[3] * vv[3];
  for (int m = 1; m < 64; m <<= 1) { s += __shfl_xor(s, m); s2 += __shfl_xor(s2, m); }
  __shared__ float ss[4], ss2[4];
  const int w = threadIdx.x >> 6;
  if ((threadIdx.x & 63) == 0) { ss[w] = s; ss2[w] = s2; }
  __syncthreads();
  s = ss[0] + ss[1] + ss[2] + ss[3];
  s2 = ss2[0] + ss2[1] + ss2[2] + ss2[3];
  const float mu = s * (1.0f / 1024.0f);
  const float var = s2 * (1.0f / 1024.0f) - mu * mu;
  const float r = rsqrtf(var + 1e-5f);
  const int c = threadIdx.x * 4;
  const float4 g4 = ((const float4*)g)[threadIdx.x];
  const float4 b4 = ((const float4*)b)[threadIdx.x];
  float gg[4] = {g4.x, g4.y, g4.z, g4.w};
  float bb[4] = {b4.x, b4.y, b4.z, b4.w};
  u16 o[4];
  for (int j = 0; j < 4; ++j) o[j] = f2bf((vv[j] - mu) * r * gg[j] + bb[j]);
  ((ushort4*)(out + (size_t)row * 1024 + c))[0] = *(ushort4*)o;
}

// ---------------- GEMM small: 128x128, 4 waves (256 thr), wave = 64x64 ------
// R21: LDS-read amplification cut. 8-wave 64x32/wave grid read 96KB/iter
// (A 4x, B 2x amplified) vs ~128 B/cy/CU LDS ceiling -> ~1040cy of the
// 2600cy iter. 64x64/wave (2x2 grid) reads 64KB/iter (-33%). 2-buffer 64KB
// -> 2 blocks/CU: same 8 waves/CU TLP but two independent barrier domains
// (block B covers block A's barrier stalls). Same 16B XOR swizzle algebra:
// srow = t>>3 in [0,32), quarters at +32 rows keep schunk valid (32 % 8 == 0).
template<bool RES_F32, bool GELU>
__global__ __launch_bounds__(256, 2)
void gemm_kernel(const u16* __restrict__ A, const u16* __restrict__ Bt,
                 const float* __restrict__ bias, const float* __restrict__ res,
                 void* __restrict__ Cout, int M, int N, int K) {
  __shared__ u16 As[2][128][64];
  __shared__ u16 Bs[2][128][64];
  const int t = threadIdx.x, lane = t & 63, w = t >> 6;   // w in 0..3
  const int wr = w >> 1, wc = w & 1;
  const int gx = gridDim.x;
  const int nwg = gx * gridDim.y;
  const int orig = blockIdx.y * gx + blockIdx.x;
  const int q8 = nwg >> 3;
  const int wgid = (orig & 7) * q8 + (orig >> 3);   // contiguous chunk per XCD
  const int m0 = (wgid / gx) * 128, n0 = (wgid % gx) * 128;
  const int fr = lane & 15, fg = lane >> 4;
  const int srow = t >> 3;                  // 0..31
  const int schunk = (t & 7) ^ (srow & 7);  // valid for rows srow + 32*q
  const u16* Ag = &A[(size_t)(m0 + srow) * K + schunk * 8];
  const u16* Bg = &Bt[(size_t)(n0 + srow) * K + schunk * 8];
  const size_t r32 = (size_t)32 * K;
  f32x4 acc[4][4] = {};
  #pragma unroll
  for (int q = 0; q < 4; ++q) {   // prologue: tile 0 (8 loads/thread)
    g2l16(Ag + q * r32, &As[0][q * 32 + w * 8][0]);
    g2l16(Bg + q * r32, &Bs[0][q * 32 + w * 8][0]);
  }
  const int nt = K >> 6;
  int c = 0;
  for (int ti = 0; ti < nt; ++ti) {
    __builtin_amdgcn_s_barrier();   // all waves done reading buf c^1
    if (ti + 1 < nt) {
      const int nx = c ^ 1;
      const size_t kn = (size_t)(ti + 1) * 64;
      #pragma unroll
      for (int q = 0; q < 4; ++q) {
        g2l16(Ag + q * r32 + kn, &As[nx][q * 32 + w * 8][0]);
        g2l16(Bg + q * r32 + kn, &Bs[nx][q * 32 + w * 8][0]);
      }
      asm volatile("s_waitcnt vmcnt(8)" ::: "memory");   // my tile-ti loads done
    } else {
      asm volatile("s_waitcnt vmcnt(0)" ::: "memory");
    }
    __builtin_amdgcn_s_barrier();   // ALL waves' tile-ti loads landed
    __builtin_amdgcn_sched_barrier(0);
    #pragma unroll
    for (int kk = 0; kk < 2; ++kk) {
      bf16x8 af[4], bfr[4];
      #pragma unroll
      for (int m = 0; m < 4; ++m) {
        const int row = wr * 64 + m * 16 + fr;
        af[m] = *(bf16x8*)&As[c][row][((kk * 4 + fg) ^ (fr & 7)) * 8];
      }
      #pragma unroll
      for (int n = 0; n < 4; ++n) {
        const int row = wc * 64 + n * 16 + fr;
        bfr[n] = *(bf16x8*)&Bs[c][row][((kk * 4 + fg) ^ (fr & 7)) * 8];
      }
      __builtin_amdgcn_s_setprio(1);
      #pragma unroll
      for (int m = 0; m < 4; ++m)
        #pragma unroll
        for (int n = 0; n < 4; ++n)
          acc[m][n] = __builtin_amdgcn_mfma_f32_16x16x32_bf16(af[m], bfr[n], acc[m][n], 0, 0, 0);
      __builtin_amdgcn_s_setprio(0);
    }
    c ^= 1;
  }
  #pragma unroll
  for (int m = 0; m < 4; ++m)
    #pragma unroll
    for (int n = 0; n < 4; ++n) {
      const int col = n0 + wc * 64 + n * 16 + fr;
      const float bv = bias ? bias[col] : 0.0f;
      #pragma unroll
      for (int i = 0; i < 4; ++i) {
        const int row = m0 + wr * 64 + m * 16 + fg * 4 + i;
        float v = acc[m][n][i] + bv;
        if (GELU) v = 0.5f * v * (1.0f + erf_fast(v * 0.70710678118654752f));
        if (RES_F32)
          ((float*)Cout)[(size_t)row * N + col] = res[(size_t)row * N + col] + v;
        else
          ((u16*)Cout)[(size_t)row * N + col] = f2bf(v);
      }
    }
}

// ---------------- GEMM big: 256x256, BK=64, XOR-swizzled full-line staging --
// (unchanged from round 16; fast poly erf in GELU epilogue)
template<bool GELU>
__global__ __launch_bounds__(512, 2)
void gemm_big_kernel(const u16* __restrict__ A, const u16* __restrict__ Bt,
                     const float* __restrict__ bias, void* __restrict__ Cout,
                     int M, int N, int K) {
  __shared__ u16 As[2][256][64];
  __shared__ u16 Bs[2][256][64];
  const int t = threadIdx.x, lane = t & 63, w = t >> 6;
  const int wr = w >> 2, wc = w & 3;
  const int gx = gridDim.x;
  const int nwg = gx * gridDim.y;
  const int orig = blockIdx.y * gx + blockIdx.x;
  const int q8 = nwg >> 3;
  const int wgid = (orig & 7) * q8 + (orig >> 3);   // contiguous chunk per XCD
  const int m0 = (wgid / gx) * 256, n0 = (wgid % gx) * 256;
  const int fr = lane & 15, fg = lane >> 4;
  const int srow = t >> 3;                    // 0..63
  const int schunk = (t & 7) ^ (srow & 7);    // same for rows srow+64i
  const u16* Ag = &A[(size_t)(m0 + srow) * K + schunk * 8];
  const u16* Bg = &Bt[(size_t)(n0 + srow) * K + schunk * 8];
  const size_t r64 = (size_t)64 * K;
  f32x4 acc[8][4] = {};
  #pragma unroll
  for (int i = 0; i < 4; ++i) {   // prologue: tile 0 (8 loads/thread)
    g2l16(Ag + i * r64, &As[0][i * 64 + w * 8][0]);
    g2l16(Bg + i * r64, &Bs[0][i * 64 + w * 8][0]);
  }
  const int nt = K >> 6;
  int c = 0;
  for (int ti = 0; ti < nt; ++ti) {
    __builtin_amdgcn_s_barrier();   // all waves done reading buf c^1
    if (ti + 1 < nt) {
      const int nx = c ^ 1;
      const size_t kn = (size_t)(ti + 1) * 64;
      #pragma unroll
      for (int i = 0; i < 4; ++i) {
        g2l16(Ag + i * r64 + kn, &As[nx][i * 64 + w * 8][0]);
        g2l16(Bg + i * r64 + kn, &Bs[nx][i * 64 + w * 8][0]);
      }
      asm volatile("s_waitcnt vmcnt(8)" ::: "memory");   // my tile-ti loads done
    } else {
      asm volatile("s_waitcnt vmcnt(0)" ::: "memory");
    }
    __builtin_amdgcn_s_barrier();   // ALL waves' tile-ti loads landed
    __builtin_amdgcn_sched_barrier(0);
    #pragma unroll
    for (int kk = 0; kk < 2; ++kk) {
      bf16x8 af[8], bfr[4];
      #pragma unroll
      for (int m = 0; m < 8; ++m) {
        const int row = wr * 128 + m * 16 + fr;
        af[m] = *(bf16x8*)&As[c][row][((kk * 4 + fg) ^ (fr & 7)) * 8];
      }
      #pragma unroll
      for (int n = 0; n < 4; ++n) {
        const int row = wc * 64 + n * 16 + fr;
        bfr[n] = *(bf16x8*)&Bs[c][row][((kk * 4 + fg) ^ (fr & 7)) * 8];
      }
      __builtin_amdgcn_s_setprio(1);
      #pragma unroll
      for (int m = 0; m < 8; ++m)
        #pragma unroll
        for (int n = 0; n < 4; ++n)
          acc[m][n] = __builtin_amdgcn_mfma_f32_16x16x32_bf16(af[m], bfr[n], acc[m][n], 0, 0, 0);
      __builtin_amdgcn_s_setprio(0);
    }
    c ^= 1;
  }
  #pragma unroll
  for (int m = 0; m < 8; ++m)
    #pragma unroll
    for (int n = 0; n < 4; ++n) {
      const int col = n0 + wc * 64 + n * 16 + fr;
      const float bv = bias ? bias[col] : 0.0f;
      #pragma unroll
      for (int i = 0; i < 4; ++i) {
        const int row = m0 + wr * 128 + m * 16 + fg * 4 + i;
        float v = acc[m][n][i] + bv;
        if (GELU) v = 0.5f * v * (1.0f + erf_fast(v * 0.70710678118654752f));
        ((u16*)Cout)[(size_t)row * N + col] = f2bf(v);
      }
    }
}

// ---------------- Flash attention, swapped-QK^T, K staged in LDS ------------
// (unchanged from round 18: causal qy load-balance remap)
template<bool CAUSAL>
__global__ __launch_bounds__(512)
void attn_kernel(const u16* __restrict__ Q, int ldq,
                 const u16* __restrict__ K, int ldk,
                 const u16* __restrict__ V, int ldv,
                 u16* __restrict__ O) {
  __shared__ u16 Ks[2][64][64];    // [buf][key][dim-chunk ^ (key&7)]
  __shared__ u16 VsT[2][64][64];   // [buf][dim][key ^ swz]
  __shared__ u16 Ps[8][16][72];    // [wave][q][key], stride 72 u16
  const int bh = blockIdx.x, b = bh >> 4, h = bh & 15;
  const int yy = blockIdx.y;
  const int qy = (yy & 1) ? ((yy - 1) >> 1) : (7 - (yy >> 1));
  const int t = threadIdx.x, w = t >> 6, lane = t & 63;
  const int ql = lane & 15;
  const int hi = lane >> 4;
  const int qr = qy * 128 + w * 16;
  const int qz = qr + ql;
  const int hcol = h * 64;
  const int nkt = CAUSAL ? 2 * qy + 2 : 16;
  const int wlim = CAUSAL ? (qr >> 6) : nkt - 1;
  const u16* Kb = K + (size_t)(b * 1024) * ldk + hcol;
  const u16* Vb = V + (size_t)(b * 1024) * ldv + hcol;
  const size_t qgrow = (size_t)(b * 1024 + qz) * ldq + hcol;
  const bf16x8 qb0 = *(const bf16x8*)&Q[qgrow + hi * 8];
  const bf16x8 qb1 = *(const bf16x8*)&Q[qgrow + 32 + hi * 8];
  f32x4 o[4] = {};
  float mrow = -1e30f, lsum = 0.0f;
  const u16* Ksrc = &Kb[(size_t)(t >> 3) * ldk + (size_t)(((t & 7) ^ ((t >> 3) & 7)) * 8)];
  const int sp = t >> 3, sm = t & 7;
  const float c1 = 0.125f * 1.44269504f;
  g2l16(Ksrc, &Ks[0][w * 8][0]);
  if (t < 256) {
    const bf16x8 va = *(const bf16x8*)&Vb[(size_t)(2 * sp) * ldv + 8 * sm];
    const bf16x8 vb = *(const bf16x8*)&Vb[(size_t)(2 * sp + 1) * ldv + 8 * sm];
    #pragma unroll
    for (int jj = 0; jj < 8; ++jj) {
      u32 pr = (u32)((const u16*)&va)[jj] | ((u32)((const u16*)&vb)[jj] << 16);
      *(u32*)&VsT[0][8 * sm + jj][(2 * sp) ^ ((jj ^ sm) << 3)] = pr;
    }
  }
  __syncthreads();

  for (int kt = 0; kt < nkt; ++kt) {
    const int cur = kt & 1, nx = cur ^ 1;
    const int k0 = kt * 64;
    bf16x8 va, vb;
    const bool havenext = (kt + 1 < nkt);
    if (havenext) {
      g2l16(Ksrc + (size_t)(k0 + 64) * ldk, &Ks[nx][w * 8][0]);
      if (t < 256) {
        va = *(const bf16x8*)&Vb[(size_t)(k0 + 64 + 2 * sp) * ldv + 8 * sm];
        vb = *(const bf16x8*)&Vb[(size_t)(k0 + 64 + 2 * sp + 1) * ldv + 8 * sm];
      }
    }
    if (kt <= wlim) {
      bf16x8 kf[8];
      const int sz = ql & 7;
      #pragma unroll
      for (int j = 0; j < 4; ++j) {
        kf[j]     = *(const bf16x8*)&Ks[cur][j * 16 + ql][(hi ^ sz) << 3];
        kf[4 + j] = *(const bf16x8*)&Ks[cur][j * 16 + ql][((hi + 4) ^ sz) << 3];
      }
      f32x4 s[4] = {};
      __builtin_amdgcn_s_setprio(1);
      #pragma unroll
      for (int j = 0; j < 4; ++j)
        s[j] = __builtin_amdgcn_mfma_f32_16x16x32_bf16(kf[j], qb0, s[j], 0, 0, 0);
      #pragma unroll
      for (int j = 0; j < 4; ++j)
        s[j] = __builtin_amdgcn_mfma_f32_16x16x32_bf16(kf[4 + j], qb1, s[j], 0, 0, 0);
      __builtin_amdgcn_s_setprio(0);
      float e2[4][4];
      float rm = -1e30f;
      const bool domask = CAUSAL && (kt == wlim);
      #pragma unroll
      for (int j = 0; j < 4; ++j)
        #pragma unroll
        for (int i = 0; i < 4; ++i) {
          float a = s[j][i] * c1;
          if (domask && (k0 + j * 16 + hi * 4 + i > qz)) a = -1e30f;
          e2[j][i] = a;
          rm = fmaxf(rm, a);
        }
      if (!__all(rm <= mrow + 8.0f)) {   // T13 defer-max
        rm = fmaxf(rm, __shfl_xor(rm, 16));
        rm = fmaxf(rm, __shfl_xor(rm, 32));
        const float mn = fmaxf(mrow, rm);
        const float sc = exp2f(mrow - mn);
        lsum *= sc;
        float scv[4];
        #pragma unroll
        for (int i = 0; i < 4; ++i) scv[i] = __shfl(sc, hi * 4 + i);
        #pragma unroll
        for (int nb = 0; nb < 4; ++nb)
          #pragma unroll
          for (int i = 0; i < 4; ++i) o[nb][i] *= scv[i];
        mrow = mn;
      }
      float p[4][4];
      #pragma unroll
      for (int j = 0; j < 4; ++j)
        #pragma unroll
        for (int i = 0; i < 4; ++i) { p[j][i] = exp2f(e2[j][i] - mrow); lsum += p[j][i]; }
      #pragma unroll
      for (int j = 0; j < 4; ++j) {
        *(u32*)&Ps[w][ql][j * 16 + hi * 4]     = cvtpk(p[j][0], p[j][1]);
        *(u32*)&Ps[w][ql][j * 16 + hi * 4 + 2] = cvtpk(p[j][2], p[j][3]);
      }
      asm volatile("s_waitcnt lgkmcnt(0)" ::: "memory");
      __builtin_amdgcn_sched_barrier(0);
      const bf16x8 pa0 = *(const bf16x8*)&Ps[w][ql][hi * 8];
      const bf16x8 pa1 = *(const bf16x8*)&Ps[w][ql][32 + hi * 8];
      __builtin_amdgcn_s_setprio(1);
      #pragma unroll
      for (int nb = 0; nb < 4; ++nb) {
        const int dim = nb * 16 + ql;
        const int swz = ((dim & 7) ^ ((dim >> 3) & 7)) << 3;
        const bf16x8 v0 = *(const bf16x8*)&VsT[cur][dim][(hi * 8) ^ swz];
        const bf16x8 v1 = *(const bf16x8*)&VsT[cur][dim][(32 + hi * 8) ^ swz];
        o[nb] = __builtin_amdgcn_mfma_f32_16x16x32_bf16(pa0, v0, o[nb], 0, 0, 0);
        o[nb] = __builtin_amdgcn_mfma_f32_16x16x32_bf16(pa1, v1, o[nb], 0, 0, 0);
      }
      __builtin_amdgcn_s_setprio(0);
    }
    if (havenext && t < 256) {
      #pragma unroll
      for (int jj = 0; jj < 8; ++jj) {
        u32 pr = (u32)((const u16*)&va)[jj] | ((u32)((const u16*)&vb)[jj] << 16);
        *(u32*)&VsT[nx][8 * sm + jj][(2 * sp) ^ ((jj ^ sm) << 3)] = pr;
      }
    }
    __syncthreads();
  }

  float ltot = lsum + __shfl_xor(lsum, 16);
  ltot += __shfl_xor(ltot, 32);
  const float inv = 1.0f / ltot;
  #pragma unroll
  for (int i = 0; i < 4; ++i) {
    const float invq = __shfl(inv, hi * 4 + i);
    const size_t row = (size_t)(b * 1024 + qr + hi * 4 + i);
    #pragma unroll
    for (int nb = 0; nb < 4; ++nb)
      O[row * 1024 + hcol + nb * 16 + ql] = f2bf(o[nb][i] * invq);
  }
}

// ---------------------------------------------------------------------------
extern "C" void kernel_launch(void* const* d_in, const int* in_sizes, int n_in,
                              void* d_out, int out_size, void* d_ws, size_t ws_size,
                              hipStream_t stream) {
  const float* dec  = (const float*)d_in[0];
  const float* enc  = (const float*)d_in[1];
  const float* sa_g = (const float*)d_in[4];
  const float* sa_b = (const float*)d_in[5];
  const float* sa_wq = (const float*)d_in[6];
  const float* sa_bq = (const float*)d_in[7];
  const float* sa_wk = (const float*)d_in[8];
  const float* sa_wv = (const float*)d_in[9];
  const float* sa_bv = (const float*)d_in[10];
  const float* sa_wo = (const float*)d_in[11];
  const float* sa_bo = (const float*)d_in[12];
  const float* ca_g = (const float*)d_in[13];
  const float* ca_b = (const float*)d_in[14];
  const float* ca_wq = (const float*)d_in[15];
  const float* ca_bq = (const float*)d_in[16];
  const float* ca_wk = (const float*)d_in[17];
  const float* ca_wv = (const float*)d_in[18];
  const float* ca_bv = (const float*)d_in[19];
  const float* ca_wo = (const float*)d_in[20];
  const float* ca_bo = (const float*)d_in[21];
  const float* mlp_g = (const float*)d_in[22];
  const float* mlp_b = (const float*)d_in[23];
  const float* w1 = (const float*)d_in[24];
  const float* b1 = (const float*)d_in[25];
  const float* w2 = (const float*)d_in[26];
  const float* b2 = (const float*)d_in[27];

  const size_t MB = 1024 * 1024;
  if (ws_size < 97 * MB) return;
  char* ws = (char*)d_ws;
  // persistent weights
  u16* WQKV = (u16*)(ws + 0 * MB);           // [3072][1024]
  u16* CQT  = (u16*)(ws + 6 * MB);           // [1024][1024]
  u16* CKV  = (u16*)(ws + 8 * MB);           // [2048][1024]
  u16* WOT  = (u16*)(ws + 12 * MB);
  u16* COT  = (u16*)(ws + 14 * MB);
  float* B3 = (float*)(ws + 16 * MB);        // 3072 f32
  float* B2 = (float*)(ws + 16 * MB + 16384);// 2048 f32
  // activations (aliased across stages)
  u16* XLN  = (u16*)(ws + 17 * MB);          // [4096][1024]
  u16* AO   = (u16*)(ws + 25 * MB);          // [4096][1024]; stage C: W1T
  u16* W1T  = (u16*)(ws + 25 * MB);          // (stage C)
  u16* ENC  = (u16*)(ws + 33 * MB);          // [4096][1024]; stage C: part of H1
  u16* FB   = (u16*)(ws + 41 * MB);          // [4096][3072] (stage A)
  u16* EF   = (u16*)(ws + 41 * MB);          // [4096][2048] (stage B)
  u16* CQB  = (u16*)(ws + 57 * MB);          // [4096][1024] (stage B)
  u16* H1   = (u16*)(ws + 33 * MB);          // [4096][4096] (stage C, over ENC+FB)
  float* X1 = (float*)(ws + 65 * MB);        // [4096][1024] f32; stage C: W2T
  u16* W2T  = (u16*)(ws + 65 * MB);          // (stage C)
  float* X2 = (float*)(ws + 81 * MB);        // [4096][1024] f32
  float* OUT = (float*)d_out;

  const dim3 blk(256), gblk(512);
  // ---- weight prep ----
  TC8 tc;
  tc.s[0] = sa_wq; tc.d[0] = WQKV;
  tc.s[1] = sa_wk; tc.d[1] = WQKV + 1024 * 1024;
  tc.s[2] = sa_wv; tc.d[2] = WQKV + 2048 * 1024;
  tc.s[3] = sa_wo; tc.d[3] = WOT;
  tc.s[4] = ca_wq; tc.d[4] = CQT;
  tc.s[5] = ca_wk; tc.d[5] = CKV;
  tc.s[6] = ca_wv; tc.d[6] = CKV + 1024 * 1024;
  tc.s[7] = ca_wo; tc.d[7] = COT;
  transcvt8_kernel<<<dim3(32, 32, 8), blk, 0, stream>>>(tc);
  pack_bias_kernel<<<dim3(20), blk, 0, stream>>>(sa_bq, sa_bv, ca_bv, B3, B2);
  cvt_kernel<<<dim3(4096), blk, 0, stream>>>(enc, ENC);

  // ---- self-attention block ----
  ln_kernel<<<dim3(4096), blk, 0, stream>>>(dec, sa_g, sa_b, XLN);
  gemm_big_kernel<false><<<dim3(12, 16), gblk, 0, stream>>>(XLN, WQKV, B3, FB, 4096, 3072, 1024);
  attn_kernel<true><<<dim3(64, 8), gblk, 0, stream>>>(FB, 3072, FB + 1024, 3072, FB + 2048, 3072, AO);
  gemm_kernel<true, false><<<dim3(8, 32), blk, 0, stream>>>(AO, WOT, sa_bo, dec, X1, 4096, 1024, 1024);

  // ---- cross-attention block ----
  ln_kernel<<<dim3(4096), blk, 0, stream>>>(X1, ca_g, ca_b, XLN);
  gemm_big_kernel<false><<<dim3(8, 16), gblk, 0, stream>>>(ENC, CKV, B2, EF, 4096, 2048, 1024);
  gemm_kernel<false, false><<<dim3(8, 32), blk, 0, stream>>>(XLN, CQT, ca_bq, nullptr, CQB, 4096, 1024, 1024);
  attn_kernel<false><<<dim3(64, 8), gblk, 0, stream>>>(CQB, 1024, EF, 2048, EF + 1024, 2048, AO);
  gemm_kernel<true, false><<<dim3(8, 32), blk, 0, stream>>>(AO, COT, ca_bo, X1, X2, 4096, 1024, 1024);

  // ---- FFN block ----
  transcvt_kernel<<<dim3(128, 32), blk, 0, stream>>>(w1, W1T, 1024, 4096);
  transcvt_kernel<<<dim3(32, 128), blk, 0, stream>>>(w2, W2T, 4096, 1024);
  ln_kernel<<<dim3(4096), blk, 0, stream>>>(X2, mlp_g, mlp_b, XLN);
  gemm_big_kernel<true><<<dim3(16, 16), gblk, 0, stream>>>(XLN, W1T, b1, H1, 4096, 4096, 1024);
  gemm_kernel<true, false><<<dim3(8, 32), blk, 0, stream>>>(H1, W2T, b2, X2, OUT, 4096, 1024, 4096);
}

// Round 22
// 369.092 us; speedup vs baseline: 1.0416x; 1.0416x over previous
//
#include <hip/hip_runtime.h>
#include <math.h>

typedef unsigned short u16;
typedef unsigned int   u32;
typedef __attribute__((ext_vector_type(8))) short bf16x8;  // 8 bf16 (4 VGPRs)
typedef __attribute__((ext_vector_type(4))) float f32x4;

__device__ __forceinline__ u16 f2bf(float f) {
  u32 u = __builtin_bit_cast(u32, f);
  u += 0x7fffu + ((u >> 16) & 1u);   // RNE
  return (u16)(u >> 16);
}
__device__ __forceinline__ u32 cvtpk(float lo, float hi_) {
  u32 r;
  asm("v_cvt_pk_bf16_f32 %0, %1, %2" : "=v"(r) : "v"(lo), "v"(hi_));
  return r;
}
// Abramowitz-Stegun 7.1.26, |err| < 1.5e-7 (negligible vs bf16 rounding)
__device__ __forceinline__ float erf_fast(float x) {
  const float ax = fabsf(x);
  const float tt = 1.0f / fmaf(0.3275911f, ax, 1.0f);
  float p = fmaf(1.061405429f, tt, -1.453152027f);
  p = fmaf(p, tt, 1.421413741f);
  p = fmaf(p, tt, -0.284496736f);
  p = fmaf(p, tt, 0.254829592f);
  const float r = 1.0f - p * tt * __expf(-ax * ax);
  return copysignf(r, x);
}

// async global->LDS, 16B per lane. LDS dest must be wave-uniform; HW writes
// lane l's 16B at dest + l*16 (linear). Global src is per-lane.
__device__ __forceinline__ void g2l16(const u16* g, u16* l) {
  __builtin_amdgcn_global_load_lds(
      (const __attribute__((address_space(1))) unsigned int*)g,
      (__attribute__((address_space(3))) unsigned int*)l, 16, 0, 0);
}

// ---------------- batched transpose+convert for 8x [1024][1024] weights ------
struct TC8 { const float* s[8]; u16* d[8]; };
__global__ __launch_bounds__(256)
void transcvt8_kernel(TC8 p) {
  const float* __restrict__ W = p.s[blockIdx.z];
  u16* __restrict__ Wt = p.d[blockIdx.z];
  __shared__ float tile[32][33];
  const int n0 = blockIdx.x * 32, k0 = blockIdx.y * 32;
  const int tx = threadIdx.x & 31, ty = threadIdx.x >> 5;  // 32 x 8
  for (int i = 0; i < 4; ++i)
    tile[ty + 8 * i][tx] = W[(size_t)(k0 + ty + 8 * i) * 1024 + n0 + tx];
  __syncthreads();
  for (int i = 0; i < 4; ++i)
    Wt[(size_t)(n0 + ty + 8 * i) * 1024 + k0 + tx] = f2bf(tile[tx][ty + 8 * i]);
}

// ---------------- transpose + convert: W[K][N] f32 -> Wt[N][K] bf16 ----------
__global__ __launch_bounds__(256)
void transcvt_kernel(const float* __restrict__ W, u16* __restrict__ Wt, int K, int N) {
  __shared__ float tile[32][33];
  const int n0 = blockIdx.x * 32, k0 = blockIdx.y * 32;
  const int tx = threadIdx.x & 31, ty = threadIdx.x >> 5;
  for (int i = 0; i < 4; ++i)
    tile[ty + 8 * i][tx] = W[(size_t)(k0 + ty + 8 * i) * N + n0 + tx];
  __syncthreads();
  for (int i = 0; i < 4; ++i)
    Wt[(size_t)(n0 + ty + 8 * i) * K + k0 + tx] = f2bf(tile[tx][ty + 8 * i]);
}

// ---------------- elementwise convert f32 -> bf16 ----------------------------
__global__ __launch_bounds__(256)
void cvt_kernel(const float* __restrict__ in, u16* __restrict__ out) {
  const int i = blockIdx.x * 256 + threadIdx.x;
  const float4 v = ((const float4*)in)[i];
  u16 o[4] = {f2bf(v.x), f2bf(v.y), f2bf(v.z), f2bf(v.w)};
  ((ushort4*)out)[i] = *(ushort4*)o;
}

// ---------------- bias packing (B3: [bq|0|bv], B2: [0|bv]) ------------------
__global__ __launch_bounds__(256)
void pack_bias_kernel(const float* __restrict__ bq, const float* __restrict__ bv,
                      const float* __restrict__ cbv,
                      float* __restrict__ B3, float* __restrict__ B2) {
  const int i = blockIdx.x * 256 + threadIdx.x;   // 5120 total
  if (i < 3072) {
    float v = 0.0f;
    if (i < 1024) v = bq[i];
    else if (i >= 2048) v = bv[i - 2048];
    B3[i] = v;
  } else {
    const int j = i - 3072;
    B2[j] = (j >= 1024) ? cbv[j - 1024] : 0.0f;
  }
}

// ---------------- LayerNorm: rows of 1024, f32 in -> bf16 out ---------------
__global__ __launch_bounds__(256)
void ln_kernel(const float* __restrict__ x, const float* __restrict__ g,
               const float* __restrict__ b, u16* __restrict__ out) {
  const int row = blockIdx.x;
  const float4 v4 = ((const float4*)(x + (size_t)row * 1024))[threadIdx.x];
  float vv[4] = {v4.x, v4.y, v4.z, v4.w};
  float s = vv[0] + vv[1] + vv[2] + vv[3];
  float s2 = vv[0] * vv[0] + vv[1] * vv[1] + vv[2] * vv[2] + vv[3] * vv[3];
  for (int m = 1; m < 64; m <<= 1) { s += __shfl_xor(s, m); s2 += __shfl_xor(s2, m); }
  __shared__ float ss[4], ss2[4];
  const int w = threadIdx.x >> 6;
  if ((threadIdx.x & 63) == 0) { ss[w] = s; ss2[w] = s2; }
  __syncthreads();
  s = ss[0] + ss[1] + ss[2] + ss[3];
  s2 = ss2[0] + ss2[1] + ss2[2] + ss2[3];
  const float mu = s * (1.0f / 1024.0f);
  const float var = s2 * (1.0f / 1024.0f) - mu * mu;
  const float r = rsqrtf(var + 1e-5f);
  const int c = threadIdx.x * 4;
  const float4 g4 = ((const float4*)g)[threadIdx.x];
  const float4 b4 = ((const float4*)b)[threadIdx.x];
  float gg[4] = {g4.x, g4.y, g4.z, g4.w};
  float bb[4] = {b4.x, b4.y, b4.z, b4.w};
  u16 o[4];
  for (int j = 0; j < 4; ++j) o[j] = f2bf((vv[j] - mu) * r * gg[j] + bb[j]);
  ((ushort4*)(out + (size_t)row * 1024 + c))[0] = *(ushort4*)o;
}

// ---------------- GEMM small: 128x128, BK=64, 16B XOR swizzle, tri-buffer ---
// (R20/R18 verified-best configuration. R21's 64x64-wave-tile regressed:
// grid = 256 blocks = 1 block/CU, so 4-wave blocks halved TLP with no
// second block to overlap. 8 waves, tri-buffer 2-ahead, conflict-free.)
template<bool RES_F32, bool GELU>
__global__ __launch_bounds__(512)
void gemm_kernel(const u16* __restrict__ A, const u16* __restrict__ Bt,
                 const float* __restrict__ bias, const float* __restrict__ res,
                 void* __restrict__ Cout, int M, int N, int K) {
  __shared__ u16 As[3][128][64];
  __shared__ u16 Bs[3][128][64];
  const int t = threadIdx.x, lane = t & 63, w = t >> 6;
  const int wr = w >> 2, wc = w & 3;
  const int gx = gridDim.x;
  const int nwg = gx * gridDim.y;
  const int orig = blockIdx.y * gx + blockIdx.x;
  const int q8 = nwg >> 3;
  const int wgid = (orig & 7) * q8 + (orig >> 3);   // contiguous chunk per XCD
  const int m0 = (wgid / gx) * 128, n0 = (wgid % gx) * 128;
  const int fr = lane & 15, fg = lane >> 4;
  const int srow = t >> 3;
  const int schunk = (t & 7) ^ (srow & 7);
  const u16* Ag = &A[(size_t)(m0 + srow) * K + schunk * 8];
  const u16* Bg = &Bt[(size_t)(n0 + srow) * K + schunk * 8];
  const size_t r64 = (size_t)64 * K;
  f32x4 acc[4][2] = {};
  #pragma unroll
  for (int ti0 = 0; ti0 < 2; ++ti0) {   // prologue: tiles 0,1 -> bufs 0,1
    const size_t kk = (size_t)ti0 * 64;
    g2l16(Ag + kk,       &As[ti0][w * 8][0]);
    g2l16(Ag + r64 + kk, &As[ti0][64 + w * 8][0]);
    g2l16(Bg + kk,       &Bs[ti0][w * 8][0]);
    g2l16(Bg + r64 + kk, &Bs[ti0][64 + w * 8][0]);
  }
  const int nt = K >> 6;
  int c = 0;
  for (int ti = 0; ti < nt; ++ti) {
    if (ti + 1 < nt) asm volatile("s_waitcnt vmcnt(4)" ::: "memory");
    else             asm volatile("s_waitcnt vmcnt(0)" ::: "memory");
    __builtin_amdgcn_s_barrier();     // tile ti landed (all waves) + buf reuse safe
    __builtin_amdgcn_sched_barrier(0);
    if (ti + 2 < nt) {                // stage ti+2 into buf read at iter ti-1
      const int nx = (c + 2 >= 3) ? c - 1 : c + 2;
      const size_t kn = (size_t)(ti + 2) * 64;
      g2l16(Ag + kn,       &As[nx][w * 8][0]);
      g2l16(Ag + r64 + kn, &As[nx][64 + w * 8][0]);
      g2l16(Bg + kn,       &Bs[nx][w * 8][0]);
      g2l16(Bg + r64 + kn, &Bs[nx][64 + w * 8][0]);
    }
    bf16x8 af[2][4], bfr[2][2];
    #pragma unroll
    for (int kk = 0; kk < 2; ++kk) {
      #pragma unroll
      for (int m = 0; m < 4; ++m) {
        const int row = wr * 64 + m * 16 + fr;
        af[kk][m] = *(bf16x8*)&As[c][row][((kk * 4 + fg) ^ (fr & 7)) * 8];
      }
      #pragma unroll
      for (int n = 0; n < 2; ++n) {
        const int row = wc * 32 + n * 16 + fr;
        bfr[kk][n] = *(bf16x8*)&Bs[c][row][((kk * 4 + fg) ^ (fr & 7)) * 8];
      }
    }
    __builtin_amdgcn_s_setprio(1);
    #pragma unroll
    for (int kk = 0; kk < 2; ++kk)
      #pragma unroll
      for (int m = 0; m < 4; ++m)
        #pragma unroll
        for (int n = 0; n < 2; ++n)
          acc[m][n] = __builtin_amdgcn_mfma_f32_16x16x32_bf16(af[kk][m], bfr[kk][n], acc[m][n], 0, 0, 0);
    __builtin_amdgcn_s_setprio(0);
    c = (c + 1 == 3) ? 0 : c + 1;
  }
  #pragma unroll
  for (int m = 0; m < 4; ++m)
    #pragma unroll
    for (int n = 0; n < 2; ++n) {
      const int col = n0 + wc * 32 + n * 16 + fr;
      const float bv = bias ? bias[col] : 0.0f;
      #pragma unroll
      for (int i = 0; i < 4; ++i) {
        const int row = m0 + wr * 64 + m * 16 + fg * 4 + i;
        float v = acc[m][n][i] + bv;
        if (GELU) v = 0.5f * v * (1.0f + erf_fast(v * 0.70710678118654752f));
        if (RES_F32)
          ((float*)Cout)[(size_t)row * N + col] = res[(size_t)row * N + col] + v;
        else
          ((u16*)Cout)[(size_t)row * N + col] = f2bf(v);
      }
    }
}

// ---------------- GEMM big: 256x256, BK=64, XOR-swizzled full-line staging --
// (unchanged from round 16; fast poly erf in GELU epilogue)
template<bool GELU>
__global__ __launch_bounds__(512, 2)
void gemm_big_kernel(const u16* __restrict__ A, const u16* __restrict__ Bt,
                     const float* __restrict__ bias, void* __restrict__ Cout,
                     int M, int N, int K) {
  __shared__ u16 As[2][256][64];
  __shared__ u16 Bs[2][256][64];
  const int t = threadIdx.x, lane = t & 63, w = t >> 6;
  const int wr = w >> 2, wc = w & 3;
  const int gx = gridDim.x;
  const int nwg = gx * gridDim.y;
  const int orig = blockIdx.y * gx + blockIdx.x;
  const int q8 = nwg >> 3;
  const int wgid = (orig & 7) * q8 + (orig >> 3);   // contiguous chunk per XCD
  const int m0 = (wgid / gx) * 256, n0 = (wgid % gx) * 256;
  const int fr = lane & 15, fg = lane >> 4;
  const int srow = t >> 3;                    // 0..63
  const int schunk = (t & 7) ^ (srow & 7);    // same for rows srow+64i
  const u16* Ag = &A[(size_t)(m0 + srow) * K + schunk * 8];
  const u16* Bg = &Bt[(size_t)(n0 + srow) * K + schunk * 8];
  const size_t r64 = (size_t)64 * K;
  f32x4 acc[8][4] = {};
  #pragma unroll
  for (int i = 0; i < 4; ++i) {   // prologue: tile 0 (8 loads/thread)
    g2l16(Ag + i * r64, &As[0][i * 64 + w * 8][0]);
    g2l16(Bg + i * r64, &Bs[0][i * 64 + w * 8][0]);
  }
  const int nt = K >> 6;
  int c = 0;
  for (int ti = 0; ti < nt; ++ti) {
    __builtin_amdgcn_s_barrier();   // all waves done reading buf c^1
    if (ti + 1 < nt) {
      const int nx = c ^ 1;
      const size_t kn = (size_t)(ti + 1) * 64;
      #pragma unroll
      for (int i = 0; i < 4; ++i) {
        g2l16(Ag + i * r64 + kn, &As[nx][i * 64 + w * 8][0]);
        g2l16(Bg + i * r64 + kn, &Bs[nx][i * 64 + w * 8][0]);
      }
      asm volatile("s_waitcnt vmcnt(8)" ::: "memory");   // my tile-ti loads done
    } else {
      asm volatile("s_waitcnt vmcnt(0)" ::: "memory");
    }
    __builtin_amdgcn_s_barrier();   // ALL waves' tile-ti loads landed
    __builtin_amdgcn_sched_barrier(0);
    #pragma unroll
    for (int kk = 0; kk < 2; ++kk) {
      bf16x8 af[8], bfr[4];
      #pragma unroll
      for (int m = 0; m < 8; ++m) {
        const int row = wr * 128 + m * 16 + fr;
        af[m] = *(bf16x8*)&As[c][row][((kk * 4 + fg) ^ (fr & 7)) * 8];
      }
      #pragma unroll
      for (int n = 0; n < 4; ++n) {
        const int row = wc * 64 + n * 16 + fr;
        bfr[n] = *(bf16x8*)&Bs[c][row][((kk * 4 + fg) ^ (fr & 7)) * 8];
      }
      __builtin_amdgcn_s_setprio(1);
      #pragma unroll
      for (int m = 0; m < 8; ++m)
        #pragma unroll
        for (int n = 0; n < 4; ++n)
          acc[m][n] = __builtin_amdgcn_mfma_f32_16x16x32_bf16(af[m], bfr[n], acc[m][n], 0, 0, 0);
      __builtin_amdgcn_s_setprio(0);
    }
    c ^= 1;
  }
  #pragma unroll
  for (int m = 0; m < 8; ++m)
    #pragma unroll
    for (int n = 0; n < 4; ++n) {
      const int col = n0 + wc * 64 + n * 16 + fr;
      const float bv = bias ? bias[col] : 0.0f;
      #pragma unroll
      for (int i = 0; i < 4; ++i) {
        const int row = m0 + wr * 128 + m * 16 + fg * 4 + i;
        float v = acc[m][n][i] + bv;
        if (GELU) v = 0.5f * v * (1.0f + erf_fast(v * 0.70710678118654752f));
        ((u16*)Cout)[(size_t)row * N + col] = f2bf(v);
      }
    }
}

// ---------------- Flash attention, swapped-QK^T, K staged in LDS ------------
// (unchanged from round 18: causal qy load-balance remap)
template<bool CAUSAL>
__global__ __launch_bounds__(512)
void attn_kernel(const u16* __restrict__ Q, int ldq,
                 const u16* __restrict__ K, int ldk,
                 const u16* __restrict__ V, int ldv,
                 u16* __restrict__ O) {
  __shared__ u16 Ks[2][64][64];    // [buf][key][dim-chunk ^ (key&7)]
  __shared__ u16 VsT[2][64][64];   // [buf][dim][key ^ swz]
  __shared__ u16 Ps[8][16][72];    // [wave][q][key], stride 72 u16
  const int bh = blockIdx.x, b = bh >> 4, h = bh & 15;
  const int yy = blockIdx.y;
  const int qy = (yy & 1) ? ((yy - 1) >> 1) : (7 - (yy >> 1));
  const int t = threadIdx.x, w = t >> 6, lane = t & 63;
  const int ql = lane & 15;
  const int hi = lane >> 4;
  const int qr = qy * 128 + w * 16;
  const int qz = qr + ql;
  const int hcol = h * 64;
  const int nkt = CAUSAL ? 2 * qy + 2 : 16;
  const int wlim = CAUSAL ? (qr >> 6) : nkt - 1;
  const u16* Kb = K + (size_t)(b * 1024) * ldk + hcol;
  const u16* Vb = V + (size_t)(b * 1024) * ldv + hcol;
  const size_t qgrow = (size_t)(b * 1024 + qz) * ldq + hcol;
  const bf16x8 qb0 = *(const bf16x8*)&Q[qgrow + hi * 8];
  const bf16x8 qb1 = *(const bf16x8*)&Q[qgrow + 32 + hi * 8];
  f32x4 o[4] = {};
  float mrow = -1e30f, lsum = 0.0f;
  const u16* Ksrc = &Kb[(size_t)(t >> 3) * ldk + (size_t)(((t & 7) ^ ((t >> 3) & 7)) * 8)];
  const int sp = t >> 3, sm = t & 7;
  const float c1 = 0.125f * 1.44269504f;
  g2l16(Ksrc, &Ks[0][w * 8][0]);
  if (t < 256) {
    const bf16x8 va = *(const bf16x8*)&Vb[(size_t)(2 * sp) * ldv + 8 * sm];
    const bf16x8 vb = *(const bf16x8*)&Vb[(size_t)(2 * sp + 1) * ldv + 8 * sm];
    #pragma unroll
    for (int jj = 0; jj < 8; ++jj) {
      u32 pr = (u32)((const u16*)&va)[jj] | ((u32)((const u16*)&vb)[jj] << 16);
      *(u32*)&VsT[0][8 * sm + jj][(2 * sp) ^ ((jj ^ sm) << 3)] = pr;
    }
  }
  __syncthreads();

  for (int kt = 0; kt < nkt; ++kt) {
    const int cur = kt & 1, nx = cur ^ 1;
    const int k0 = kt * 64;
    bf16x8 va, vb;
    const bool havenext = (kt + 1 < nkt);
    if (havenext) {
      g2l16(Ksrc + (size_t)(k0 + 64) * ldk, &Ks[nx][w * 8][0]);
      if (t < 256) {
        va = *(const bf16x8*)&Vb[(size_t)(k0 + 64 + 2 * sp) * ldv + 8 * sm];
        vb = *(const bf16x8*)&Vb[(size_t)(k0 + 64 + 2 * sp + 1) * ldv + 8 * sm];
      }
    }
    if (kt <= wlim) {
      bf16x8 kf[8];
      const int sz = ql & 7;
      #pragma unroll
      for (int j = 0; j < 4; ++j) {
        kf[j]     = *(const bf16x8*)&Ks[cur][j * 16 + ql][(hi ^ sz) << 3];
        kf[4 + j] = *(const bf16x8*)&Ks[cur][j * 16 + ql][((hi + 4) ^ sz) << 3];
      }
      f32x4 s[4] = {};
      __builtin_amdgcn_s_setprio(1);
      #pragma unroll
      for (int j = 0; j < 4; ++j)
        s[j] = __builtin_amdgcn_mfma_f32_16x16x32_bf16(kf[j], qb0, s[j], 0, 0, 0);
      #pragma unroll
      for (int j = 0; j < 4; ++j)
        s[j] = __builtin_amdgcn_mfma_f32_16x16x32_bf16(kf[4 + j], qb1, s[j], 0, 0, 0);
      __builtin_amdgcn_s_setprio(0);
      float e2[4][4];
      float rm = -1e30f;
      const bool domask = CAUSAL && (kt == wlim);
      #pragma unroll
      for (int j = 0; j < 4; ++j)
        #pragma unroll
        for (int i = 0; i < 4; ++i) {
          float a = s[j][i] * c1;
          if (domask && (k0 + j * 16 + hi * 4 + i > qz)) a = -1e30f;
          e2[j][i] = a;
          rm = fmaxf(rm, a);
        }
      if (!__all(rm <= mrow + 8.0f)) {   // T13 defer-max
        rm = fmaxf(rm, __shfl_xor(rm, 16));
        rm = fmaxf(rm, __shfl_xor(rm, 32));
        const float mn = fmaxf(mrow, rm);
        const float sc = exp2f(mrow - mn);
        lsum *= sc;
        float scv[4];
        #pragma unroll
        for (int i = 0; i < 4; ++i) scv[i] = __shfl(sc, hi * 4 + i);
        #pragma unroll
        for (int nb = 0; nb < 4; ++nb)
          #pragma unroll
          for (int i = 0; i < 4; ++i) o[nb][i] *= scv[i];
        mrow = mn;
      }
      float p[4][4];
      #pragma unroll
      for (int j = 0; j < 4; ++j)
        #pragma unroll
        for (int i = 0; i < 4; ++i) { p[j][i] = exp2f(e2[j][i] - mrow); lsum += p[j][i]; }
      #pragma unroll
      for (int j = 0; j < 4; ++j) {
        *(u32*)&Ps[w][ql][j * 16 + hi * 4]     = cvtpk(p[j][0], p[j][1]);
        *(u32*)&Ps[w][ql][j * 16 + hi * 4 + 2] = cvtpk(p[j][2], p[j][3]);
      }
      asm volatile("s_waitcnt lgkmcnt(0)" ::: "memory");
      __builtin_amdgcn_sched_barrier(0);
      const bf16x8 pa0 = *(const bf16x8*)&Ps[w][ql][hi * 8];
      const bf16x8 pa1 = *(const bf16x8*)&Ps[w][ql][32 + hi * 8];
      __builtin_amdgcn_s_setprio(1);
      #pragma unroll
      for (int nb = 0; nb < 4; ++nb) {
        const int dim = nb * 16 + ql;
        const int swz = ((dim & 7) ^ ((dim >> 3) & 7)) << 3;
        const bf16x8 v0 = *(const bf16x8*)&VsT[cur][dim][(hi * 8) ^ swz];
        const bf16x8 v1 = *(const bf16x8*)&VsT[cur][dim][(32 + hi * 8) ^ swz];
        o[nb] = __builtin_amdgcn_mfma_f32_16x16x32_bf16(pa0, v0, o[nb], 0, 0, 0);
        o[nb] = __builtin_amdgcn_mfma_f32_16x16x32_bf16(pa1, v1, o[nb], 0, 0, 0);
      }
      __builtin_amdgcn_s_setprio(0);
    }
    if (havenext && t < 256) {
      #pragma unroll
      for (int jj = 0; jj < 8; ++jj) {
        u32 pr = (u32)((const u16*)&va)[jj] | ((u32)((const u16*)&vb)[jj] << 16);
        *(u32*)&VsT[nx][8 * sm + jj][(2 * sp) ^ ((jj ^ sm) << 3)] = pr;
      }
    }
    __syncthreads();
  }

  float ltot = lsum + __shfl_xor(lsum, 16);
  ltot += __shfl_xor(ltot, 32);
  const float inv = 1.0f / ltot;
  #pragma unroll
  for (int i = 0; i < 4; ++i) {
    const float invq = __shfl(inv, hi * 4 + i);
    const size_t row = (size_t)(b * 1024 + qr + hi * 4 + i);
    #pragma unroll
    for (int nb = 0; nb < 4; ++nb)
      O[row * 1024 + hcol + nb * 16 + ql] = f2bf(o[nb][i] * invq);
  }
}

// ---------------------------------------------------------------------------
extern "C" void kernel_launch(void* const* d_in, const int* in_sizes, int n_in,
                              void* d_out, int out_size, void* d_ws, size_t ws_size,
                              hipStream_t stream) {
  const float* dec  = (const float*)d_in[0];
  const float* enc  = (const float*)d_in[1];
  const float* sa_g = (const float*)d_in[4];
  const float* sa_b = (const float*)d_in[5];
  const float* sa_wq = (const float*)d_in[6];
  const float* sa_bq = (const float*)d_in[7];
  const float* sa_wk = (const float*)d_in[8];
  const float* sa_wv = (const float*)d_in[9];
  const float* sa_bv = (const float*)d_in[10];
  const float* sa_wo = (const float*)d_in[11];
  const float* sa_bo = (const float*)d_in[12];
  const float* ca_g = (const float*)d_in[13];
  const float* ca_b = (const float*)d_in[14];
  const float* ca_wq = (const float*)d_in[15];
  const float* ca_bq = (const float*)d_in[16];
  const float* ca_wk = (const float*)d_in[17];
  const float* ca_wv = (const float*)d_in[18];
  const float* ca_bv = (const float*)d_in[19];
  const float* ca_wo = (const float*)d_in[20];
  const float* ca_bo = (const float*)d_in[21];
  const float* mlp_g = (const float*)d_in[22];
  const float* mlp_b = (const float*)d_in[23];
  const float* w1 = (const float*)d_in[24];
  const float* b1 = (const float*)d_in[25];
  const float* w2 = (const float*)d_in[26];
  const float* b2 = (const float*)d_in[27];

  const size_t MB = 1024 * 1024;
  if (ws_size < 97 * MB) return;
  char* ws = (char*)d_ws;
  // persistent weights
  u16* WQKV = (u16*)(ws + 0 * MB);           // [3072][1024]
  u16* CQT  = (u16*)(ws + 6 * MB);           // [1024][1024]
  u16* CKV  = (u16*)(ws + 8 * MB);           // [2048][1024]
  u16* WOT  = (u16*)(ws + 12 * MB);
  u16* COT  = (u16*)(ws + 14 * MB);
  float* B3 = (float*)(ws + 16 * MB);        // 3072 f32
  float* B2 = (float*)(ws + 16 * MB + 16384);// 2048 f32
  // activations (aliased across stages)
  u16* XLN  = (u16*)(ws + 17 * MB);          // [4096][1024]
  u16* AO   = (u16*)(ws + 25 * MB);          // [4096][1024]; stage C: W1T
  u16* W1T  = (u16*)(ws + 25 * MB);          // (stage C)
  u16* ENC  = (u16*)(ws + 33 * MB);          // [4096][1024]; stage C: part of H1
  u16* FB   = (u16*)(ws + 41 * MB);          // [4096][3072] (stage A)
  u16* EF   = (u16*)(ws + 41 * MB);          // [4096][2048] (stage B)
  u16* CQB  = (u16*)(ws + 57 * MB);          // [4096][1024] (stage B)
  u16* H1   = (u16*)(ws + 33 * MB);          // [4096][4096] (stage C, over ENC+FB)
  float* X1 = (float*)(ws + 65 * MB);        // [4096][1024] f32; stage C: W2T
  u16* W2T  = (u16*)(ws + 65 * MB);          // (stage C)
  float* X2 = (float*)(ws + 81 * MB);        // [4096][1024] f32
  float* OUT = (float*)d_out;

  const dim3 blk(256), gblk(512), ablk(512);
  // ---- weight prep ----
  TC8 tc;
  tc.s[0] = sa_wq; tc.d[0] = WQKV;
  tc.s[1] = sa_wk; tc.d[1] = WQKV + 1024 * 1024;
  tc.s[2] = sa_wv; tc.d[2] = WQKV + 2048 * 1024;
  tc.s[3] = sa_wo; tc.d[3] = WOT;
  tc.s[4] = ca_wq; tc.d[4] = CQT;
  tc.s[5] = ca_wk; tc.d[5] = CKV;
  tc.s[6] = ca_wv; tc.d[6] = CKV + 1024 * 1024;
  tc.s[7] = ca_wo; tc.d[7] = COT;
  transcvt8_kernel<<<dim3(32, 32, 8), blk, 0, stream>>>(tc);
  pack_bias_kernel<<<dim3(20), blk, 0, stream>>>(sa_bq, sa_bv, ca_bv, B3, B2);
  cvt_kernel<<<dim3(4096), blk, 0, stream>>>(enc, ENC);

  // ---- self-attention block ----
  ln_kernel<<<dim3(4096), blk, 0, stream>>>(dec, sa_g, sa_b, XLN);
  gemm_big_kernel<false><<<dim3(12, 16), gblk, 0, stream>>>(XLN, WQKV, B3, FB, 4096, 3072, 1024);
  attn_kernel<true><<<dim3(64, 8), ablk, 0, stream>>>(FB, 3072, FB + 1024, 3072, FB + 2048, 3072, AO);
  gemm_kernel<true, false><<<dim3(8, 32), gblk, 0, stream>>>(AO, WOT, sa_bo, dec, X1, 4096, 1024, 1024);

  // ---- cross-attention block ----
  ln_kernel<<<dim3(4096), blk, 0, stream>>>(X1, ca_g, ca_b, XLN);
  gemm_big_kernel<false><<<dim3(8, 16), gblk, 0, stream>>>(ENC, CKV, B2, EF, 4096, 2048, 1024);
  gemm_kernel<false, false><<<dim3(8, 32), gblk, 0, stream>>>(XLN, CQT, ca_bq, nullptr, CQB, 4096, 1024, 1024);
  attn_kernel<false><<<dim3(64, 8), ablk, 0, stream>>>(CQB, 1024, EF, 2048, EF + 1024, 2048, AO);
  gemm_kernel<true, false><<<dim3(8, 32), gblk, 0, stream>>>(AO, COT, ca_bo, X1, X2, 4096, 1024, 1024);

  // ---- FFN block ----
  transcvt_kernel<<<dim3(128, 32), blk, 0, stream>>>(w1, W1T, 1024, 4096);
  transcvt_kernel<<<dim3(32, 128), blk, 0, stream>>>(w2, W2T, 4096, 1024);
  ln_kernel<<<dim3(4096), blk, 0, stream>>>(X2, mlp_g, mlp_b, XLN);
  gemm_big_kernel<true><<<dim3(16, 16), gblk, 0, stream>>>(XLN, W1T, b1, H1, 4096, 4096, 1024);
  gemm_kernel<true, false><<<dim3(8, 32), gblk, 0, stream>>>(H1, W2T, b2, X2, OUT, 4096, 1024, 4096);
}